// Round 3
// baseline (403.835 us; speedup 1.0000x reference)
//
#include <hip/hip_runtime.h>

// WOQ int4-asym (tinygemm) linear: out[64,8192] = x @ dequant(w).T
// R3: two-stage. Theory: R2's direct weight loads scatter 64 lanes across 16
// rows x 32KB stride (bad DRAM pattern, ~2 TB/s eff) -> gemm ~145us vs 42us
// floor. Stage 1 streams qw fully sequentially and packs 8 int32 -> 1 dword
// of nibbles into d_ws (288 MB total traffic ~46us). Stage 2 = same MFMA gemm
// but B-frag = ONE dword/lane from the 32 MB packed array (L3-resident).
// Partials + reduce epilogue unchanged.

#define OUT_F 8192
#define IN_F  8192
#define M_TOK 64
#define GROUP 128
#define BN    128             // n per block: 4 waves x 32
#define KSPLIT 16
#define KR    (IN_F / KSPLIT) // 512 k per block
#define PW_DW (IN_F / 8)      // 1024 packed dwords per row

typedef short short8 __attribute__((ext_vector_type(8)));
typedef float f32x4  __attribute__((ext_vector_type(4)));
typedef int   int4v  __attribute__((ext_vector_type(4)));

// pack two fp32 -> two bf16 (round-half-up) in one int
__device__ __forceinline__ int pack_bf2(float lo, float hi) {
    unsigned ul = __float_as_uint(lo) + 0x8000u;
    unsigned uh = __float_as_uint(hi) + 0x8000u;
    return (int)((ul >> 16) | (uh & 0xFFFF0000u));
}

// ---------- stage 1: sequential repack int32 -> 4-bit nibbles ----------
__global__ __launch_bounds__(256)
void woq_pack(const int* __restrict__ qw, unsigned* __restrict__ pw) {
    const int tid = blockIdx.x * 256 + threadIdx.x;   // one output dword each
    const int4* p = (const int4*)(qw + (size_t)tid * 8);
    int4 a = p[0];
    int4 b = p[1];
    unsigned w = (unsigned)a.x        | ((unsigned)a.y << 4)
               | ((unsigned)a.z << 8) | ((unsigned)a.w << 12)
               | ((unsigned)b.x << 16)| ((unsigned)b.y << 20)
               | ((unsigned)b.z << 24)| ((unsigned)b.w << 28);
    pw[tid] = w;
}

// ---------- stage 2: MFMA gemm from packed weights ----------
__global__ __launch_bounds__(256, 4)
void woq_gemm_packed(const float*    __restrict__ x,
                     const unsigned* __restrict__ pw,
                     const float*    __restrict__ sz,
                     float*          __restrict__ outp) {
    __shared__ int lds_x[16 * 64 * 4];   // 16 chunks x 64 lanes x 16 B = 16 KB

    const int t    = threadIdx.x;
    const int lane = t & 63;
    const int wv   = t >> 6;          // wave 0..3
    const int n0   = blockIdx.x * BN; // n tile base
    const int k0   = blockIdx.y * KR; // k range base

    const int nlo  = lane & 15;
    const int quad = lane >> 4;

    const int n1 = n0 + wv * 32 + nlo;
    const int n2 = n1 + 16;
    const unsigned* pw1 = pw + (size_t)n1 * PW_DW + quad;
    const unsigned* pw2 = pw + (size_t)n2 * PW_DW + quad;

    f32x4 acc[4][2];
#pragma unroll
    for (int mi = 0; mi < 4; ++mi)
#pragma unroll
        for (int ni = 0; ni < 2; ++ni)
            acc[mi][ni] = (f32x4){0.f, 0.f, 0.f, 0.f};

    for (int g = 0; g < KR / GROUP; ++g) {
        const int kg = k0 + g * GROUP;
        const int gg = kg >> 7;       // global group index

        // per-group scale / (zp - 8*scale) for this lane's two n values
        const float2 p1 = *(const float2*)(sz + ((size_t)gg * OUT_F + n1) * 2);
        const float2 p2 = *(const float2*)(sz + ((size_t)gg * OUT_F + n2) * 2);
        const float s1 = p1.x, c1 = fmaf(-8.f, p1.x, p1.y);
        const float s2 = p2.x, c2 = fmaf(-8.f, p2.x, p2.y);

        __syncthreads();
        // stage x[0:64][kg:kg+128] as bf16 in frag order:
        // slot (chunk = ks*4+mi, l): x[mi*16 + (l&15)][ks*32 + (l>>4)*8 + j]
#pragma unroll
        for (int i = 0; i < 4; ++i) {
            int slot  = t + 256 * i;          // 0..1023
            int chunk = slot >> 6;
            int l     = slot & 63;
            int m     = ((chunk & 3) << 4) + (l & 15);
            int kk    = ((chunk >> 2) << 5) + ((l >> 4) << 3);
            const float4* p = (const float4*)(x + (size_t)m * IN_F + kg + kk);
            float4 v0 = p[0];
            float4 v1 = p[1];
            int4v bv;
            bv.x = pack_bf2(v0.x, v0.y);
            bv.y = pack_bf2(v0.z, v0.w);
            bv.z = pack_bf2(v1.x, v1.y);
            bv.w = pack_bf2(v1.z, v1.w);
            *(int4v*)&lds_x[slot * 4] = bv;
        }
        __syncthreads();

        const int dwg = kg >> 3;      // packed-dword base of this group

#pragma unroll
        for (int ks = 0; ks < 4; ++ks) {
            // --- B: one packed dword per lane per n (8 nibbles = 8 k) ---
            const unsigned w1 = pw1[dwg + ks * 4];
            const unsigned w2 = pw2[dwg + ks * 4];

            // --- A frags from LDS (conflict-free b128) ---
            short8 a[4];
#pragma unroll
            for (int mi = 0; mi < 4; ++mi)
                a[mi] = *(const short8*)&lds_x[((ks * 4 + mi) * 64 + lane) * 4];

            // --- dequant 8 nibbles -> bf16 ---
            float v1f[8], v2f[8];
#pragma unroll
            for (int j = 0; j < 8; ++j) {
                v1f[j] = fmaf((float)((w1 >> (4 * j)) & 15u), s1, c1);
                v2f[j] = fmaf((float)((w2 >> (4 * j)) & 15u), s2, c2);
            }
            int4v b1i, b2i;
            b1i.x = pack_bf2(v1f[0], v1f[1]);
            b1i.y = pack_bf2(v1f[2], v1f[3]);
            b1i.z = pack_bf2(v1f[4], v1f[5]);
            b1i.w = pack_bf2(v1f[6], v1f[7]);
            b2i.x = pack_bf2(v2f[0], v2f[1]);
            b2i.y = pack_bf2(v2f[2], v2f[3]);
            b2i.z = pack_bf2(v2f[4], v2f[5]);
            b2i.w = pack_bf2(v2f[6], v2f[7]);
            short8 b1 = __builtin_bit_cast(short8, b1i);
            short8 b2 = __builtin_bit_cast(short8, b2i);

#pragma unroll
            for (int mi = 0; mi < 4; ++mi) {
                acc[mi][0] = __builtin_amdgcn_mfma_f32_16x16x32_bf16(a[mi], b1, acc[mi][0], 0, 0, 0);
                acc[mi][1] = __builtin_amdgcn_mfma_f32_16x16x32_bf16(a[mi], b2, acc[mi][1], 0, 0, 0);
            }
        }
    }

    // epilogue: C/D layout col = lane&15, row = quad*4 + r
    float* dst = outp + (size_t)blockIdx.y * (M_TOK * OUT_F);
#pragma unroll
    for (int mi = 0; mi < 4; ++mi) {
#pragma unroll
        for (int ni = 0; ni < 2; ++ni) {
            const int n = n0 + wv * 32 + ni * 16 + nlo;
#pragma unroll
            for (int r = 0; r < 4; ++r) {
                const int m = mi * 16 + quad * 4 + r;
                dst[(size_t)m * OUT_F + n] = acc[mi][ni][r];
            }
        }
    }
}

// ---------- fallback (ws too small): direct gemm with atomics (R2 path) ----------
__global__ __launch_bounds__(256, 4)
void woq_gemm_atomic(const float* __restrict__ x,
                     const int*   __restrict__ qw,
                     const float* __restrict__ sz,
                     float*       __restrict__ outp) {
    __shared__ int lds_x[16 * 64 * 4];
    const int t = threadIdx.x, lane = t & 63, wv = t >> 6;
    const int n0 = blockIdx.x * BN, k0 = blockIdx.y * KR;
    const int nlo = lane & 15, quad = lane >> 4, kq8 = quad << 3;
    const int n1 = n0 + wv * 32 + nlo, n2 = n1 + 16;
    f32x4 acc[4][2];
#pragma unroll
    for (int mi = 0; mi < 4; ++mi)
#pragma unroll
        for (int ni = 0; ni < 2; ++ni) acc[mi][ni] = (f32x4){0.f, 0.f, 0.f, 0.f};
    for (int g = 0; g < KR / GROUP; ++g) {
        const int kg = k0 + g * GROUP, gg = kg >> 7;
        const float2 p1 = *(const float2*)(sz + ((size_t)gg * OUT_F + n1) * 2);
        const float2 p2 = *(const float2*)(sz + ((size_t)gg * OUT_F + n2) * 2);
        const float s1 = p1.x, c1 = fmaf(-8.f, p1.x, p1.y);
        const float s2 = p2.x, c2 = fmaf(-8.f, p2.x, p2.y);
        __syncthreads();
#pragma unroll
        for (int i = 0; i < 4; ++i) {
            int slot = t + 256 * i, chunk = slot >> 6, l = slot & 63;
            int m = ((chunk & 3) << 4) + (l & 15);
            int kk = ((chunk >> 2) << 5) + ((l >> 4) << 3);
            const float4* p = (const float4*)(x + (size_t)m * IN_F + kg + kk);
            float4 v0 = p[0], v1 = p[1];
            int4v bv;
            bv.x = pack_bf2(v0.x, v0.y); bv.y = pack_bf2(v0.z, v0.w);
            bv.z = pack_bf2(v1.x, v1.y); bv.w = pack_bf2(v1.z, v1.w);
            *(int4v*)&lds_x[slot * 4] = bv;
        }
        __syncthreads();
#pragma unroll
        for (int ks = 0; ks < 4; ++ks) {
            const int k = kg + ks * 32;
            const int* q1p = qw + (size_t)n1 * IN_F + k + kq8;
            const int* q2p = qw + (size_t)n2 * IN_F + k + kq8;
            const int4 qa = *(const int4*)(q1p), qb = *(const int4*)(q1p + 4);
            const int4 qc = *(const int4*)(q2p), qd = *(const int4*)(q2p + 4);
            short8 a[4];
#pragma unroll
            for (int mi = 0; mi < 4; ++mi)
                a[mi] = *(const short8*)&lds_x[((ks * 4 + mi) * 64 + lane) * 4];
            int4v b1i, b2i;
            b1i.x = pack_bf2(fmaf((float)qa.x, s1, c1), fmaf((float)qa.y, s1, c1));
            b1i.y = pack_bf2(fmaf((float)qa.z, s1, c1), fmaf((float)qa.w, s1, c1));
            b1i.z = pack_bf2(fmaf((float)qb.x, s1, c1), fmaf((float)qb.y, s1, c1));
            b1i.w = pack_bf2(fmaf((float)qb.z, s1, c1), fmaf((float)qb.w, s1, c1));
            b2i.x = pack_bf2(fmaf((float)qc.x, s2, c2), fmaf((float)qc.y, s2, c2));
            b2i.y = pack_bf2(fmaf((float)qc.z, s2, c2), fmaf((float)qc.w, s2, c2));
            b2i.z = pack_bf2(fmaf((float)qd.x, s2, c2), fmaf((float)qd.y, s2, c2));
            b2i.w = pack_bf2(fmaf((float)qd.z, s2, c2), fmaf((float)qd.w, s2, c2));
            short8 b1 = __builtin_bit_cast(short8, b1i);
            short8 b2 = __builtin_bit_cast(short8, b2i);
#pragma unroll
            for (int mi = 0; mi < 4; ++mi) {
                acc[mi][0] = __builtin_amdgcn_mfma_f32_16x16x32_bf16(a[mi], b1, acc[mi][0], 0, 0, 0);
                acc[mi][1] = __builtin_amdgcn_mfma_f32_16x16x32_bf16(a[mi], b2, acc[mi][1], 0, 0, 0);
            }
        }
    }
#pragma unroll
    for (int mi = 0; mi < 4; ++mi)
#pragma unroll
        for (int ni = 0; ni < 2; ++ni) {
            const int n = n0 + wv * 32 + ni * 16 + nlo;
#pragma unroll
            for (int r = 0; r < 4; ++r) {
                const int m = mi * 16 + quad * 4 + r;
                atomicAdd(outp + (size_t)m * OUT_F + n, acc[mi][ni][r]);
            }
        }
}

__global__ __launch_bounds__(256)
void woq_reduce(const float* __restrict__ part, float* __restrict__ out) {
    const int i = (blockIdx.x * 256 + threadIdx.x) * 4;
    const size_t stride = (size_t)M_TOK * OUT_F;
    float4 s = *(const float4*)(part + i);
#pragma unroll
    for (int k = 1; k < KSPLIT; ++k) {
        float4 v = *(const float4*)(part + (size_t)k * stride + i);
        s.x += v.x; s.y += v.y; s.z += v.z; s.w += v.w;
    }
    *(float4*)(out + i) = s;
}

extern "C" void kernel_launch(void* const* d_in, const int* in_sizes, int n_in,
                              void* d_out, int out_size, void* d_ws, size_t ws_size,
                              hipStream_t stream) {
    const float* x  = (const float*)d_in[0];
    const int*   qw = (const int*)d_in[1];
    const float* sz = (const float*)d_in[2];
    float* out = (float*)d_out;

    const size_t pw_bytes   = (size_t)OUT_F * PW_DW * sizeof(unsigned);      // 32 MB
    const size_t part_bytes = (size_t)KSPLIT * M_TOK * OUT_F * sizeof(float); // 32 MB
    dim3 grid(OUT_F / BN, KSPLIT);

    if (ws_size >= pw_bytes + part_bytes) {
        unsigned* pw  = (unsigned*)d_ws;
        float*    part = (float*)((char*)d_ws + pw_bytes);
        woq_pack<<<(OUT_F * PW_DW) / 256, 256, 0, stream>>>(qw, pw);
        woq_gemm_packed<<<grid, 256, 0, stream>>>(x, pw, sz, part);
        woq_reduce<<<(M_TOK * OUT_F) / (256 * 4), 256, 0, stream>>>(part, out);
    } else {
        hipMemsetAsync(d_out, 0, (size_t)out_size * sizeof(float), stream);
        woq_gemm_atomic<<<grid, 256, 0, stream>>>(x, qw, sz, out);
    }
}

// Round 4
// 396.760 us; speedup vs baseline: 1.0178x; 1.0178x over previous
//
#include <hip/hip_runtime.h>

// WOQ int4-asym (tinygemm) linear: out[64,8192] = x @ dequant(w).T
// R4: single-stage gemm, but qw tile staged via LDS so global weight reads
// are 2 rows x 512B contiguous per wave-instr (vs R2's 16 rows x 128B scatter
// at 32KB stride). 16B-block XOR swizzle (kb ^ (n&7)) in the LDS qw tile
// makes B-frag ds_read_b128s 2-way bank-aliased (free). KSPLIT 16->8 halves
// partial traffic. LDS 64KB(qw)+16KB(x) -> 2 blocks/CU, 8 waves/CU.
// Inferred budget: fixed harness overhead ~325us; R2 gemm ~59us vs 42us floor.

#define OUT_F 8192
#define IN_F  8192
#define M_TOK 64
#define GROUP 128
#define BN    128             // n per block: 4 waves x 32
#define KSPLIT 8
#define KR    (IN_F / KSPLIT) // 1024 k per block

typedef short short8 __attribute__((ext_vector_type(8)));
typedef float f32x4  __attribute__((ext_vector_type(4)));
typedef int   int4v  __attribute__((ext_vector_type(4)));

// pack two fp32 -> two bf16 (round-half-up) in one int
__device__ __forceinline__ int pack_bf2(float lo, float hi) {
    unsigned ul = __float_as_uint(lo) + 0x8000u;
    unsigned uh = __float_as_uint(hi) + 0x8000u;
    return (int)((ul >> 16) | (uh & 0xFFFF0000u));
}

__global__ __launch_bounds__(256, 2)
void woq_gemm(const float* __restrict__ x,
              const int*   __restrict__ qw,
              const float* __restrict__ sz,
              float*       __restrict__ part) {
    __shared__ int qtile[128 * 128];     // 64 KB: [n][swizzled kdw], 512 B/row
    __shared__ int lds_x[16 * 64 * 4];   // 16 KB: x frag-order bf16

    const int t    = threadIdx.x;
    const int lane = t & 63;
    const int wv   = t >> 6;          // wave 0..3
    const int n0   = blockIdx.x * BN; // n tile base
    const int k0   = blockIdx.y * KR; // k range base

    const int nlo  = lane & 15;
    const int quad = lane >> 4;
    const int swz  = nlo & 7;         // row XOR swizzle key (r&7 == nlo&7)

    const int r1 = wv * 32 + nlo;     // local row of first n
    const int r2 = r1 + 16;
    const int n1 = n0 + r1;
    const int n2 = n0 + r2;

    // staging assignment: chunk c = i*256+t ; row = c>>5, kb = c&31
    // -> lanes 0..31 cover row's 32 x 16B = 512 B contiguous, 2 rows/wave-instr
    const int st_row = t >> 5;        // base row (advances by 8 per i)
    const int st_kb  = t & 31;

    f32x4 acc[4][2];
#pragma unroll
    for (int mi = 0; mi < 4; ++mi)
#pragma unroll
        for (int ni = 0; ni < 2; ++ni)
            acc[mi][ni] = (f32x4){0.f, 0.f, 0.f, 0.f};

    for (int g = 0; g < KR / GROUP; ++g) {
        const int kg = k0 + g * GROUP;
        const int gg = kg >> 7;       // global group index

        const float2 p1 = *(const float2*)(sz + ((size_t)gg * OUT_F + n1) * 2);
        const float2 p2 = *(const float2*)(sz + ((size_t)gg * OUT_F + n2) * 2);
        const float s1 = p1.x, c1 = fmaf(-8.f, p1.x, p1.y);
        const float s2 = p2.x, c2 = fmaf(-8.f, p2.x, p2.y);

        __syncthreads();

        // ---- stage qw[n0:n0+128][kg:kg+128] -> qtile (swizzled) ----
        // global: contiguous 512 B per row, 2 rows per wave-instr
        int4 qbuf[16];
#pragma unroll
        for (int i = 0; i < 16; ++i) {
            const int row = st_row + i * 8;
            qbuf[i] = *(const int4*)(qw + (size_t)(n0 + row) * IN_F + kg + st_kb * 4);
        }
#pragma unroll
        for (int i = 0; i < 16; ++i) {
            const int row = st_row + i * 8;
            const int kbp = st_kb ^ (row & 7);
            *(int4v*)&qtile[row * 128 + kbp * 4] = (int4v){qbuf[i].x, qbuf[i].y, qbuf[i].z, qbuf[i].w};
        }

        // ---- stage x[0:64][kg:kg+128] as bf16 in frag order ----
#pragma unroll
        for (int i = 0; i < 4; ++i) {
            int slot  = t + 256 * i;          // 0..1023
            int chunk = slot >> 6;
            int l     = slot & 63;
            int m     = ((chunk & 3) << 4) + (l & 15);
            int kk    = ((chunk >> 2) << 5) + ((l >> 4) << 3);
            const float4* p = (const float4*)(x + (size_t)m * IN_F + kg + kk);
            float4 v0 = p[0];
            float4 v1 = p[1];
            int4v bv;
            bv.x = pack_bf2(v0.x, v0.y);
            bv.y = pack_bf2(v0.z, v0.w);
            bv.z = pack_bf2(v1.x, v1.y);
            bv.w = pack_bf2(v1.z, v1.w);
            *(int4v*)&lds_x[slot * 4] = bv;
        }
        __syncthreads();

#pragma unroll
        for (int ks = 0; ks < 4; ++ks) {
            const int kb0 = ks * 8 + quad * 2;   // 16B-block index of this lane's 8 k

            // --- B: from swizzled LDS tile (2-way bank alias = free) ---
            const int4v qa = *(const int4v*)&qtile[r1 * 128 + ((kb0     ^ swz) << 2)];
            const int4v qb = *(const int4v*)&qtile[r1 * 128 + (((kb0+1) ^ swz) << 2)];
            const int4v qc = *(const int4v*)&qtile[r2 * 128 + ((kb0     ^ swz) << 2)];
            const int4v qd = *(const int4v*)&qtile[r2 * 128 + (((kb0+1) ^ swz) << 2)];

            // --- A frags ---
            short8 a[4];
#pragma unroll
            for (int mi = 0; mi < 4; ++mi)
                a[mi] = *(const short8*)&lds_x[((ks * 4 + mi) * 64 + lane) * 4];

            // --- dequant to bf16 (pair-packed) ---
            int4v b1i, b2i;
            b1i.x = pack_bf2(fmaf((float)qa.x, s1, c1), fmaf((float)qa.y, s1, c1));
            b1i.y = pack_bf2(fmaf((float)qa.z, s1, c1), fmaf((float)qa.w, s1, c1));
            b1i.z = pack_bf2(fmaf((float)qb.x, s1, c1), fmaf((float)qb.y, s1, c1));
            b1i.w = pack_bf2(fmaf((float)qb.z, s1, c1), fmaf((float)qb.w, s1, c1));
            b2i.x = pack_bf2(fmaf((float)qc.x, s2, c2), fmaf((float)qc.y, s2, c2));
            b2i.y = pack_bf2(fmaf((float)qc.z, s2, c2), fmaf((float)qc.w, s2, c2));
            b2i.z = pack_bf2(fmaf((float)qd.x, s2, c2), fmaf((float)qd.y, s2, c2));
            b2i.w = pack_bf2(fmaf((float)qd.z, s2, c2), fmaf((float)qd.w, s2, c2));
            short8 b1 = __builtin_bit_cast(short8, b1i);
            short8 b2 = __builtin_bit_cast(short8, b2i);

#pragma unroll
            for (int mi = 0; mi < 4; ++mi) {
                acc[mi][0] = __builtin_amdgcn_mfma_f32_16x16x32_bf16(a[mi], b1, acc[mi][0], 0, 0, 0);
                acc[mi][1] = __builtin_amdgcn_mfma_f32_16x16x32_bf16(a[mi], b2, acc[mi][1], 0, 0, 0);
            }
        }
    }

    // epilogue: C/D layout col = lane&15, row = quad*4 + r
    float* dst = part + (size_t)blockIdx.y * (M_TOK * OUT_F);
#pragma unroll
    for (int mi = 0; mi < 4; ++mi) {
#pragma unroll
        for (int ni = 0; ni < 2; ++ni) {
            const int n = n0 + wv * 32 + ni * 16 + nlo;
#pragma unroll
            for (int r = 0; r < 4; ++r) {
                const int m = mi * 16 + quad * 4 + r;
                dst[(size_t)m * OUT_F + n] = acc[mi][ni][r];
            }
        }
    }
}

__global__ __launch_bounds__(256)
void woq_reduce(const float* __restrict__ part, float* __restrict__ out) {
    const int i = (blockIdx.x * 256 + threadIdx.x) * 4;
    const size_t stride = (size_t)M_TOK * OUT_F;
    float4 s = *(const float4*)(part + i);
#pragma unroll
    for (int k = 1; k < KSPLIT; ++k) {
        float4 v = *(const float4*)(part + (size_t)k * stride + i);
        s.x += v.x; s.y += v.y; s.z += v.z; s.w += v.w;
    }
    *(float4*)(out + i) = s;
}

// ---------- fallback (ws too small): direct gemm with atomics ----------
__global__ __launch_bounds__(256, 4)
void woq_gemm_atomic(const float* __restrict__ x,
                     const int*   __restrict__ qw,
                     const float* __restrict__ sz,
                     float*       __restrict__ outp) {
    __shared__ int lds_x[16 * 64 * 4];
    const int t = threadIdx.x, lane = t & 63, wv = t >> 6;
    const int n0 = blockIdx.x * BN, k0 = blockIdx.y * KR;
    const int nlo = lane & 15, quad = lane >> 4, kq8 = quad << 3;
    const int n1 = n0 + wv * 32 + nlo, n2 = n1 + 16;
    f32x4 acc[4][2];
#pragma unroll
    for (int mi = 0; mi < 4; ++mi)
#pragma unroll
        for (int ni = 0; ni < 2; ++ni) acc[mi][ni] = (f32x4){0.f, 0.f, 0.f, 0.f};
    for (int g = 0; g < KR / GROUP; ++g) {
        const int kg = k0 + g * GROUP, gg = kg >> 7;
        const float2 p1 = *(const float2*)(sz + ((size_t)gg * OUT_F + n1) * 2);
        const float2 p2 = *(const float2*)(sz + ((size_t)gg * OUT_F + n2) * 2);
        const float s1 = p1.x, c1 = fmaf(-8.f, p1.x, p1.y);
        const float s2 = p2.x, c2 = fmaf(-8.f, p2.x, p2.y);
        __syncthreads();
#pragma unroll
        for (int i = 0; i < 4; ++i) {
            int slot = t + 256 * i, chunk = slot >> 6, l = slot & 63;
            int m = ((chunk & 3) << 4) + (l & 15);
            int kk = ((chunk >> 2) << 5) + ((l >> 4) << 3);
            const float4* p = (const float4*)(x + (size_t)m * IN_F + kg + kk);
            float4 v0 = p[0], v1 = p[1];
            int4v bv;
            bv.x = pack_bf2(v0.x, v0.y); bv.y = pack_bf2(v0.z, v0.w);
            bv.z = pack_bf2(v1.x, v1.y); bv.w = pack_bf2(v1.z, v1.w);
            *(int4v*)&lds_x[slot * 4] = bv;
        }
        __syncthreads();
#pragma unroll
        for (int ks = 0; ks < 4; ++ks) {
            const int k = kg + ks * 32;
            const int* q1p = qw + (size_t)n1 * IN_F + k + kq8;
            const int* q2p = qw + (size_t)n2 * IN_F + k + kq8;
            const int4 qa = *(const int4*)(q1p), qb = *(const int4*)(q1p + 4);
            const int4 qc = *(const int4*)(q2p), qd = *(const int4*)(q2p + 4);
            short8 a[4];
#pragma unroll
            for (int mi = 0; mi < 4; ++mi)
                a[mi] = *(const short8*)&lds_x[((ks * 4 + mi) * 64 + lane) * 4];
            int4v b1i, b2i;
            b1i.x = pack_bf2(fmaf((float)qa.x, s1, c1), fmaf((float)qa.y, s1, c1));
            b1i.y = pack_bf2(fmaf((float)qa.z, s1, c1), fmaf((float)qa.w, s1, c1));
            b1i.z = pack_bf2(fmaf((float)qb.x, s1, c1), fmaf((float)qb.y, s1, c1));
            b1i.w = pack_bf2(fmaf((float)qb.z, s1, c1), fmaf((float)qb.w, s1, c1));
            b2i.x = pack_bf2(fmaf((float)qc.x, s2, c2), fmaf((float)qc.y, s2, c2));
            b2i.y = pack_bf2(fmaf((float)qc.z, s2, c2), fmaf((float)qc.w, s2, c2));
            b2i.z = pack_bf2(fmaf((float)qd.x, s2, c2), fmaf((float)qd.y, s2, c2));
            b2i.w = pack_bf2(fmaf((float)qd.z, s2, c2), fmaf((float)qd.w, s2, c2));
            short8 b1 = __builtin_bit_cast(short8, b1i);
            short8 b2 = __builtin_bit_cast(short8, b2i);
#pragma unroll
            for (int mi = 0; mi < 4; ++mi) {
                acc[mi][0] = __builtin_amdgcn_mfma_f32_16x16x32_bf16(a[mi], b1, acc[mi][0], 0, 0, 0);
                acc[mi][1] = __builtin_amdgcn_mfma_f32_16x16x32_bf16(a[mi], b2, acc[mi][1], 0, 0, 0);
            }
        }
    }
#pragma unroll
    for (int mi = 0; mi < 4; ++mi)
#pragma unroll
        for (int ni = 0; ni < 2; ++ni) {
            const int n = n0 + wv * 32 + ni * 16 + nlo;
#pragma unroll
            for (int r = 0; r < 4; ++r) {
                const int m = mi * 16 + quad * 4 + r;
                atomicAdd(outp + (size_t)m * OUT_F + n, acc[mi][ni][r]);
            }
        }
}

extern "C" void kernel_launch(void* const* d_in, const int* in_sizes, int n_in,
                              void* d_out, int out_size, void* d_ws, size_t ws_size,
                              hipStream_t stream) {
    const float* x  = (const float*)d_in[0];
    const int*   qw = (const int*)d_in[1];
    const float* sz = (const float*)d_in[2];
    float* out = (float*)d_out;

    const size_t part_bytes = (size_t)KSPLIT * M_TOK * OUT_F * sizeof(float); // 16 MB
    dim3 grid(OUT_F / BN, KSPLIT);

    if (ws_size >= part_bytes) {
        float* part = (float*)d_ws;
        woq_gemm<<<grid, 256, 0, stream>>>(x, qw, sz, part);
        woq_reduce<<<(M_TOK * OUT_F) / (256 * 4), 256, 0, stream>>>(part, out);
    } else {
        hipMemsetAsync(d_out, 0, (size_t)out_size * sizeof(float), stream);
        woq_gemm_atomic<<<grid, 256, 0, stream>>>(x, qw, sz, out);
    }
}

// Round 5
// 390.759 us; speedup vs baseline: 1.0335x; 1.0154x over previous
//
#include <hip/hip_runtime.h>

// WOQ int4-asym (tinygemm) linear: out[64,8192] = x @ dequant(w).T
// R5: revert to R2 (best measured, 390us). Session model: ~330us fixed
// harness restore/poison + ~60us kernel vs ~51us structural floor (256 MB
// int32-coded nibble stream must cross HBM once). R3 (repack) and R4
// (LDS-staged granules) both failed to beat this -> direct global->VGPR
// weight stream in MFMA B-frag layout, dequant in-register, 16x16x32 bf16
// MFMA, KSPLIT=16 partials in d_ws + float4 reduce. 4 blocks/CU.

#define OUT_F 8192
#define IN_F  8192
#define M_TOK 64
#define GROUP 128
#define BN    128             // n per block: 4 waves x 32
#define KSPLIT 16
#define KR    (IN_F / KSPLIT) // 512 k per block

typedef short short8 __attribute__((ext_vector_type(8)));
typedef float f32x4  __attribute__((ext_vector_type(4)));
typedef int   int4v  __attribute__((ext_vector_type(4)));

// pack two fp32 -> two bf16 (round-half-up) in one int
__device__ __forceinline__ int pack_bf2(float lo, float hi) {
    unsigned ul = __float_as_uint(lo) + 0x8000u;
    unsigned uh = __float_as_uint(hi) + 0x8000u;
    return (int)((ul >> 16) | (uh & 0xFFFF0000u));
}

template <bool ATOMIC>
__global__ __launch_bounds__(256, 4)
void woq_gemm(const float* __restrict__ x,
              const int*   __restrict__ qw,
              const float* __restrict__ sz,
              float*       __restrict__ outp) {
    __shared__ int lds_x[16 * 64 * 4];   // 16 chunks x 64 lanes x 16 B = 16 KB

    const int t    = threadIdx.x;
    const int lane = t & 63;
    const int wv   = t >> 6;          // wave 0..3
    const int n0   = blockIdx.x * BN; // n tile base
    const int k0   = blockIdx.y * KR; // k range base

    const int nlo  = lane & 15;
    const int quad = lane >> 4;
    const int kq8  = quad << 3;       // k offset of this lane's 8-int run

    const int n1 = n0 + wv * 32 + nlo;
    const int n2 = n1 + 16;

    f32x4 acc[4][2];
#pragma unroll
    for (int mi = 0; mi < 4; ++mi)
#pragma unroll
        for (int ni = 0; ni < 2; ++ni)
            acc[mi][ni] = (f32x4){0.f, 0.f, 0.f, 0.f};

    for (int g = 0; g < KR / GROUP; ++g) {
        const int kg = k0 + g * GROUP;
        const int gg = kg >> 7;       // global group index

        // per-group scale / (zp - 8*scale) for this lane's two n values
        const float2 p1 = *(const float2*)(sz + ((size_t)gg * OUT_F + n1) * 2);
        const float2 p2 = *(const float2*)(sz + ((size_t)gg * OUT_F + n2) * 2);
        const float s1 = p1.x, c1 = fmaf(-8.f, p1.x, p1.y);
        const float s2 = p2.x, c2 = fmaf(-8.f, p2.x, p2.y);

        __syncthreads();
        // stage x[0:64][kg:kg+128] as bf16 in frag order:
        // slot (chunk = ks*4+mi, l): x[mi*16 + (l&15)][ks*32 + (l>>4)*8 + j]
#pragma unroll
        for (int i = 0; i < 4; ++i) {
            int slot  = t + 256 * i;          // 0..1023
            int chunk = slot >> 6;
            int l     = slot & 63;
            int m     = ((chunk & 3) << 4) + (l & 15);
            int kk    = ((chunk >> 2) << 5) + ((l >> 4) << 3);
            const float4* p = (const float4*)(x + (size_t)m * IN_F + kg + kk);
            float4 v0 = p[0];
            float4 v1 = p[1];
            int4v bv;
            bv.x = pack_bf2(v0.x, v0.y);
            bv.y = pack_bf2(v0.z, v0.w);
            bv.z = pack_bf2(v1.x, v1.y);
            bv.w = pack_bf2(v1.z, v1.w);
            *(int4v*)&lds_x[slot * 4] = bv;
        }
        __syncthreads();

#pragma unroll
        for (int ks = 0; ks < 4; ++ks) {
            const int k = kg + ks * 32;

            // --- B: weight stream (the HBM-critical loads) ---
            const int* q1p = qw + (size_t)n1 * IN_F + k + kq8;
            const int* q2p = qw + (size_t)n2 * IN_F + k + kq8;
            const int4 qa = *(const int4*)(q1p);
            const int4 qb = *(const int4*)(q1p + 4);
            const int4 qc = *(const int4*)(q2p);
            const int4 qd = *(const int4*)(q2p + 4);

            // --- A frags from LDS (conflict-free b128) ---
            short8 a[4];
#pragma unroll
            for (int mi = 0; mi < 4; ++mi)
                a[mi] = *(const short8*)&lds_x[((ks * 4 + mi) * 64 + lane) * 4];

            // --- dequant to bf16 (pair-packed) ---
            int4v b1i, b2i;
            b1i.x = pack_bf2(fmaf((float)qa.x, s1, c1), fmaf((float)qa.y, s1, c1));
            b1i.y = pack_bf2(fmaf((float)qa.z, s1, c1), fmaf((float)qa.w, s1, c1));
            b1i.z = pack_bf2(fmaf((float)qb.x, s1, c1), fmaf((float)qb.y, s1, c1));
            b1i.w = pack_bf2(fmaf((float)qb.z, s1, c1), fmaf((float)qb.w, s1, c1));
            short8 b1 = __builtin_bit_cast(short8, b1i);
#pragma unroll
            for (int mi = 0; mi < 4; ++mi)
                acc[mi][0] = __builtin_amdgcn_mfma_f32_16x16x32_bf16(a[mi], b1, acc[mi][0], 0, 0, 0);

            b2i.x = pack_bf2(fmaf((float)qc.x, s2, c2), fmaf((float)qc.y, s2, c2));
            b2i.y = pack_bf2(fmaf((float)qc.z, s2, c2), fmaf((float)qc.w, s2, c2));
            b2i.z = pack_bf2(fmaf((float)qd.x, s2, c2), fmaf((float)qd.y, s2, c2));
            b2i.w = pack_bf2(fmaf((float)qd.z, s2, c2), fmaf((float)qd.w, s2, c2));
            short8 b2 = __builtin_bit_cast(short8, b2i);
#pragma unroll
            for (int mi = 0; mi < 4; ++mi)
                acc[mi][1] = __builtin_amdgcn_mfma_f32_16x16x32_bf16(a[mi], b2, acc[mi][1], 0, 0, 0);
        }
    }

    // epilogue: C/D layout col = lane&15, row = quad*4 + r
    float* dst = ATOMIC ? outp : outp + (size_t)blockIdx.y * (M_TOK * OUT_F);
#pragma unroll
    for (int mi = 0; mi < 4; ++mi) {
#pragma unroll
        for (int ni = 0; ni < 2; ++ni) {
            const int n = n0 + wv * 32 + ni * 16 + nlo;
#pragma unroll
            for (int r = 0; r < 4; ++r) {
                const int m = mi * 16 + quad * 4 + r;
                if (ATOMIC)
                    atomicAdd(dst + (size_t)m * OUT_F + n, acc[mi][ni][r]);
                else
                    dst[(size_t)m * OUT_F + n] = acc[mi][ni][r];
            }
        }
    }
}

__global__ __launch_bounds__(256)
void woq_reduce(const float* __restrict__ part, float* __restrict__ out) {
    const int i = (blockIdx.x * 256 + threadIdx.x) * 4;
    const size_t stride = (size_t)M_TOK * OUT_F;
    float4 s = *(const float4*)(part + i);
#pragma unroll
    for (int k = 1; k < KSPLIT; ++k) {
        float4 v = *(const float4*)(part + (size_t)k * stride + i);
        s.x += v.x; s.y += v.y; s.z += v.z; s.w += v.w;
    }
    *(float4*)(out + i) = s;
}

extern "C" void kernel_launch(void* const* d_in, const int* in_sizes, int n_in,
                              void* d_out, int out_size, void* d_ws, size_t ws_size,
                              hipStream_t stream) {
    const float* x  = (const float*)d_in[0];
    const int*   qw = (const int*)d_in[1];
    const float* sz = (const float*)d_in[2];
    float* out = (float*)d_out;

    dim3 grid(OUT_F / BN, KSPLIT);
    const size_t need = (size_t)KSPLIT * M_TOK * OUT_F * sizeof(float);

    if (ws_size >= need) {
        float* part = (float*)d_ws;
        woq_gemm<false><<<grid, 256, 0, stream>>>(x, qw, sz, part);
        woq_reduce<<<(M_TOK * OUT_F) / (256 * 4), 256, 0, stream>>>(part, out);
    } else {
        hipMemsetAsync(d_out, 0, (size_t)out_size * sizeof(float), stream);
        woq_gemm<true><<<grid, 256, 0, stream>>>(x, qw, sz, out);
    }
}